// Round 3
// baseline (337.429 us; speedup 1.0000x reference)
//
#include <hip/hip_runtime.h>

#define F_DIM 128
#define C_DIM 100000
#define B_ROWS 512
#define ANGLE 0.5f
#define NXB 196            // column-blocks of 512 cols
#define NBLK (4 * NXB)     // 784 total blocks
#define LBS 130            // padded lB row stride (u16): k*65%32 spreads quads -> no conflicts

typedef __attribute__((ext_vector_type(4))) float  f32x4;
typedef __attribute__((ext_vector_type(8))) short  bf16x8;
typedef __attribute__((ext_vector_type(4))) short  bf16x4;

static __device__ __forceinline__ unsigned short f2bf(float x) {
    unsigned int u = __float_as_uint(x);
    u += 0x7FFFu + ((u >> 16) & 1u);      // RNE
    return (unsigned short)(u >> 16);
}

// ---------------------------------------------------------------------------
// One fused kernel. grid (4, 196): x = 128-row group, y = 512-col block.
//  - stage A once (bf16, XOR-swizzled, conflict-free b128 frag reads)
//  - 4 column-subtiles: lB staging is register-double-buffered (prefetch t+1
//    while MFMA on t), lB padded stride kills 4-way B-frag conflicts
//  - per-block row partials -> pp[cblk][row] via agent-scope stores
//  - last block to arrive (device-scope counter) computes the target-column
//    terms + final loss in-kernel. No tail kernels.
// ---------------------------------------------------------------------------
__global__ __launch_bounds__(256, 2)
void arc_fused(const float* __restrict__ feat,
               const float* __restrict__ w,
               const int*   __restrict__ target,
               float* __restrict__ pp,        // [NXB][512]
               unsigned* counter,
               float* __restrict__ out)
{
    __shared__ unsigned short lA[128 * 128];  // [row][k] swizzled 16B chunks
    __shared__ unsigned short lB[128 * LBS];  // [k][c] padded
    __shared__ float lRow[128];
    __shared__ unsigned lastFlag;

    const int tid    = threadIdx.x;
    const int r0     = blockIdx.x * 128;
    const int cblk   = blockIdx.y;
    const int cbase0 = cblk * 512;

    if (tid < 128) lRow[tid] = 0.f;

    // ---- stage A (features) fp32 -> bf16, swizzled; once per block ----
    #pragma unroll
    for (int it = 0; it < 16; ++it) {
        const int idx4 = it * 256 + tid;
        const int row  = idx4 >> 5;
        const int c4   = idx4 & 31;
        const f32x4 v  = *(const f32x4*)(feat + (size_t)(r0 + row) * F_DIM + c4 * 4);
        bf16x4 h;
        h[0] = (short)f2bf(v[0]); h[1] = (short)f2bf(v[1]);
        h[2] = (short)f2bf(v[2]); h[3] = (short)f2bf(v[3]);
        const int pc = (c4 >> 1) ^ (row & 15);
        *(bf16x4*)&lA[row * 128 + pc * 8 + (c4 & 1) * 4] = h;
    }

    const int lane = tid & 63;
    const int wv   = tid >> 6;
    const int quad = lane >> 4;
    const int l15  = lane & 15;
    const int nb   = wv * 32;
    const int sc4  = tid & 31;      // staging: float4-col within subtile (fixed per thread)
    const int sk0  = tid >> 5;      // staging: k base (k = it*8 + sk0)

    float esum[8][4];
    #pragma unroll
    for (int m = 0; m < 8; ++m)
        #pragma unroll
        for (int r = 0; r < 4; ++r) esum[m][r] = 0.f;

    // ---- prefetch subtile 0 into registers ----
    f32x4 pre[16];
    {
        const int c = cbase0 + sc4 * 4;
        #pragma unroll
        for (int it = 0; it < 16; ++it) {
            pre[it] = (f32x4){0.f, 0.f, 0.f, 0.f};
            if (c < C_DIM)
                pre[it] = *(const f32x4*)(w + (size_t)(it * 8 + sk0) * C_DIM + c);
        }
    }

    #pragma unroll
    for (int t = 0; t < 4; ++t) {
        // ---- write prefetched subtile into lB (cvt to bf16) ----
        #pragma unroll
        for (int it = 0; it < 16; ++it) {
            bf16x4 h;
            h[0] = (short)f2bf(pre[it][0]); h[1] = (short)f2bf(pre[it][1]);
            h[2] = (short)f2bf(pre[it][2]); h[3] = (short)f2bf(pre[it][3]);
            *(bf16x4*)&lB[(it * 8 + sk0) * LBS + sc4 * 4] = h;
        }
        __syncthreads();

        // ---- prefetch subtile t+1 (overlaps MFMA below) ----
        if (t < 3) {
            const int c = cbase0 + (t + 1) * 128 + sc4 * 4;
            #pragma unroll
            for (int it = 0; it < 16; ++it) {
                pre[it] = (f32x4){0.f, 0.f, 0.f, 0.f};
                if (c < C_DIM)
                    pre[it] = *(const f32x4*)(w + (size_t)(it * 8 + sk0) * C_DIM + c);
            }
        }

        // ---- MFMA on subtile t ----
        f32x4 acc[8][2];
        #pragma unroll
        for (int m = 0; m < 8; ++m) {
            acc[m][0] = (f32x4){0.f, 0.f, 0.f, 0.f};
            acc[m][1] = (f32x4){0.f, 0.f, 0.f, 0.f};
        }
        #pragma unroll
        for (int ks = 0; ks < 4; ++ks) {
            bf16x8 bfr[2];
            #pragma unroll
            for (int s = 0; s < 2; ++s) {
                #pragma unroll
                for (int j = 0; j < 8; ++j)
                    bfr[s][j] = (short)lB[(ks * 32 + quad * 8 + j) * LBS + nb + s * 16 + l15];
            }
            #pragma unroll
            for (int m = 0; m < 8; ++m) {
                const int row = m * 16 + l15;
                const int pc  = (ks * 4 + quad) ^ (row & 15);
                const bf16x8 af = *(const bf16x8*)&lA[row * 128 + pc * 8];
                acc[m][0] = __builtin_amdgcn_mfma_f32_16x16x32_bf16(af, bfr[0], acc[m][0], 0, 0, 0);
                acc[m][1] = __builtin_amdgcn_mfma_f32_16x16x32_bf16(af, bfr[1], acc[m][1], 0, 0, 0);
            }
        }

        // ---- exp accumulate ----
        const int  col0 = cbase0 + t * 128 + nb + l15;
        const int  col1 = col0 + 16;
        const bool v0   = col0 < C_DIM;
        const bool v1   = col1 < C_DIM;
        #pragma unroll
        for (int m = 0; m < 8; ++m) {
            #pragma unroll
            for (int r = 0; r < 4; ++r) {
                if (v0) esum[m][r] += __expf(acc[m][0][r]);
                if (v1) esum[m][r] += __expf(acc[m][1][r]);
            }
        }
        __syncthreads();   // lB consumed; safe to overwrite next iter
    }

    // ---- block reduce: 16 col-lanes -> 1, cross-wave via LDS atomics ----
    #pragma unroll
    for (int m = 0; m < 8; ++m) {
        #pragma unroll
        for (int r = 0; r < 4; ++r) {
            float s = esum[m][r];
            #pragma unroll
            for (int off = 1; off < 16; off <<= 1)
                s += __shfl_xor(s, off);
            if (l15 == 0)
                atomicAdd(&lRow[m * 16 + quad * 4 + r], s);
        }
    }
    __syncthreads();

    // ---- publish partials (device-visible), arrive at counter ----
    if (tid < 128)
        __hip_atomic_store(pp + (size_t)cblk * 512 + r0 + tid, lRow[tid],
                           __ATOMIC_RELAXED, __HIP_MEMORY_SCOPE_AGENT);
    __threadfence();
    __syncthreads();
    if (tid == 0) {
        unsigned prev = __hip_atomic_fetch_add(counter, 1u,
                            __ATOMIC_ACQ_REL, __HIP_MEMORY_SCOPE_AGENT);
        lastFlag = (prev == NBLK - 1) ? 1u : 0u;
    }
    __syncthreads();
    if (lastFlag == 0u) return;
    __threadfence();

    // ======================= tail: last block only =======================
    float* lT = (float*)lA;   // reuse LDS for 512 terms
    #pragma unroll
    for (int rr = 0; rr < 2; ++rr) {
        const int b = tid + rr * 256;
        const int tg = target[b];
        float dot = 0.f, fsq = 0.f, wsq = 0.f;
        #pragma unroll 8
        for (int f = 0; f < F_DIM; ++f) {
            const float fv = feat[b * F_DIM + f];
            const float wvv = w[(size_t)f * C_DIM + tg];
            dot += fv * wvv; fsq += fv * fv; wsq += wvv * wvv;
        }
        float rs = 0.f;
        for (int j = 0; j < NXB; ++j)
            rs += __hip_atomic_load(pp + (size_t)j * 512 + b,
                                    __ATOMIC_RELAXED, __HIP_MEMORY_SCOPE_AGENT);
        const float mod = sqrtf(fsq) * sqrtf(wsq);
        float ct = dot / (mod * 1.01f);
        ct = fminf(1.f, fmaxf(-1.f, ct));
        const float th   = acosf(ct) + ANGLE;
        const float marg = mod * cosf(th);
        const float down = rs - expf(dot) + expf(marg);
        lT[b] = marg - logf(down);
    }
    __syncthreads();
    lT[tid] += lT[tid + 256];
    __syncthreads();
    #pragma unroll
    for (int st = 128; st > 0; st >>= 1) {
        if (tid < st) lT[tid] += lT[tid + st];
        __syncthreads();
    }
    if (tid == 0) out[0] = -lT[0] / (float)B_ROWS;
}

// ---------------------------------------------------------------------------
extern "C" void kernel_launch(void* const* d_in, const int* in_sizes, int n_in,
                              void* d_out, int out_size, void* d_ws, size_t ws_size,
                              hipStream_t stream)
{
    const float* feat   = (const float*)d_in[0];   // [512,128] fp32
    const float* w      = (const float*)d_in[1];   // [128,100000] fp32
    const int*   target = (const int*)d_in[2];     // [512]

    float*    pp      = (float*)d_ws;                    // [196][512]
    unsigned* counter = (unsigned*)(pp + (size_t)NXB * 512);

    hipMemsetAsync(counter, 0, sizeof(unsigned), stream);
    arc_fused<<<dim3(4, NXB), 256, 0, stream>>>(feat, w, target, pp, counter,
                                                (float*)d_out);
}

// Round 4
// 135.754 us; speedup vs baseline: 2.4856x; 2.4856x over previous
//
#include <hip/hip_runtime.h>

#define F_DIM 128
#define C_DIM 100000
#define B_ROWS 512
#define ANGLE 0.5f
#define CPB 128            // classes per block
#define NCB 782            // ceil(100000/128); last block has 96 OOB pad classes
#define OOB_PAD 96.0f      // pad classes contribute exp(0)=1 each to row sums
#define LBT_S 136          // lBt row stride in u16: 272B, even b128 bank spread

typedef __attribute__((ext_vector_type(4))) float  f32x4;
typedef __attribute__((ext_vector_type(8))) short  bf16x8;
typedef __attribute__((ext_vector_type(4))) short  bf16x4;

static __device__ __forceinline__ short f2bf(float x) {
    unsigned int u = __float_as_uint(x);
    u += 0x7FFFu + ((u >> 16) & 1u);      // RNE
    return (short)(u >> 16);
}

// ---------------------------------------------------------------------------
// arc_main: one block = ALL 512 batch rows x 128 classes; w read once grid-wide.
//   A-operand = w^T  (LDS, transposed [c][k], pad->conflict-free ds_read_b128)
//   B-operand = features (registers, 32 VGPRs/lane, loaded once; L2-resident)
//   D[m=class][n=batch]; per-lane esum over its 64 class-logits; quad-shuffle
//   reduce; direct store pp[cb][batch]. ONE barrier per block, no atomics.
// ---------------------------------------------------------------------------
__global__ __launch_bounds__(1024, 4)
void arc_main(const float* __restrict__ feat,
              const float* __restrict__ w,
              float* __restrict__ pp)        // [NCB][512]
{
    __shared__ unsigned short lBt[128 * LBT_S];   // [c][k], 34816 B

    const int tid = threadIdx.x;
    const int cb  = blockIdx.x;
    const int c0  = cb * CPB;

    // ---- stage w tile transposed: thread -> one column c, k-range g*16..+15
    {
        const int c  = tid & 127;
        const int g  = tid >> 7;              // 0..7
        const int gc = c0 + c;
        float v[16];
        #pragma unroll
        for (int i = 0; i < 16; ++i)
            v[i] = (gc < C_DIM) ? w[(size_t)(g * 16 + i) * C_DIM + gc] : 0.f;
        #pragma unroll
        for (int j = 0; j < 4; ++j) {
            bf16x4 h;
            h[0] = f2bf(v[4*j+0]); h[1] = f2bf(v[4*j+1]);
            h[2] = f2bf(v[4*j+2]); h[3] = f2bf(v[4*j+3]);
            *(bf16x4*)&lBt[c * LBT_S + g * 16 + j * 4] = h;
        }
    }

    const int lane = tid & 63;
    const int wv   = tid >> 6;                // 0..15, wave's 32-batch strip
    const int quad = lane >> 4;
    const int l15  = lane & 15;

    // ---- feature fragments in registers: fB[s][ks] = f[b][k0..k0+7]
    //      b = wv*32 + s*16 + l15, k0 = ks*32 + quad*8   (B-operand layout)
    bf16x8 fB[2][4];
    #pragma unroll
    for (int s = 0; s < 2; ++s) {
        const int b = wv * 32 + s * 16 + l15;
        #pragma unroll
        for (int ks = 0; ks < 4; ++ks) {
            const int k0 = ks * 32 + quad * 8;
            const f32x4 u0 = *(const f32x4*)(feat + b * F_DIM + k0);
            const f32x4 u1 = *(const f32x4*)(feat + b * F_DIM + k0 + 4);
            bf16x8 h;
            h[0] = f2bf(u0[0]); h[1] = f2bf(u0[1]); h[2] = f2bf(u0[2]); h[3] = f2bf(u0[3]);
            h[4] = f2bf(u1[0]); h[5] = f2bf(u1[1]); h[6] = f2bf(u1[2]); h[7] = f2bf(u1[3]);
            fB[s][ks] = h;
        }
    }
    __syncthreads();

    // ---- m-outer MFMA: acc live = 8 VGPRs only; exp folded per m-tile
    float esum0 = 0.f, esum1 = 0.f;
    #pragma unroll
    for (int m = 0; m < 8; ++m) {
        f32x4 a0 = {0.f, 0.f, 0.f, 0.f};
        f32x4 a1 = {0.f, 0.f, 0.f, 0.f};
        #pragma unroll
        for (int ks = 0; ks < 4; ++ks) {
            // A-frag: w^T[class = m*16+l15][k = ks*32+quad*8 + j]
            const bf16x8 af =
                *(const bf16x8*)&lBt[(m * 16 + l15) * LBT_S + ks * 32 + quad * 8];
            a0 = __builtin_amdgcn_mfma_f32_16x16x32_bf16(af, fB[0][ks], a0, 0, 0, 0);
            a1 = __builtin_amdgcn_mfma_f32_16x16x32_bf16(af, fB[1][ks], a1, 0, 0, 0);
        }
        #pragma unroll
        for (int r = 0; r < 4; ++r) {
            esum0 += __expf(a0[r]);
            esum1 += __expf(a1[r]);
        }
    }

    // ---- reduce across quads (same batch col), store pp[cb][batch]
    esum0 += __shfl_xor(esum0, 16); esum0 += __shfl_xor(esum0, 32);
    esum1 += __shfl_xor(esum1, 16); esum1 += __shfl_xor(esum1, 32);
    if (lane < 16) {
        pp[(size_t)cb * 512 + wv * 32 + lane]      = esum0;
        pp[(size_t)cb * 512 + wv * 32 + 16 + lane] = esum1;
    }
}

// ---------------------------------------------------------------------------
// arc_row: exact fp32 target-column terms + partial reduce. One wave per row.
// ---------------------------------------------------------------------------
__global__ void arc_row(const float* __restrict__ feat,
                        const float* __restrict__ w,
                        const int*   __restrict__ target,
                        const float* __restrict__ pp,
                        float* __restrict__ term)
{
    const int b    = blockIdx.x;
    const int lane = threadIdx.x;             // 64
    const int t    = target[b];

    float dot = 0.f, wsq = 0.f, fsq = 0.f, rs = 0.f;
    #pragma unroll
    for (int h = 0; h < 2; ++h) {
        const int f  = lane + h * 64;
        const float fv = feat[b * F_DIM + f];
        const float wv = w[(size_t)f * C_DIM + t];
        dot += fv * wv;
        wsq += wv * wv;
        fsq += fv * fv;
    }
    for (int j = lane; j < NCB; j += 64)
        rs += pp[(size_t)j * 512 + b];

    #pragma unroll
    for (int off = 32; off > 0; off >>= 1) {
        dot += __shfl_xor(dot, off);
        wsq += __shfl_xor(wsq, off);
        fsq += __shfl_xor(fsq, off);
        rs  += __shfl_xor(rs,  off);
    }
    if (lane == 0) {
        const float mod = sqrtf(fsq) * sqrtf(wsq);
        float ct = dot / (mod * 1.01f);
        ct = fminf(1.f, fmaxf(-1.f, ct));
        const float th   = acosf(ct) + ANGLE;
        const float marg = mod * cosf(th);
        const float down = rs - OOB_PAD - expf(dot) + expf(marg);
        term[b] = marg - logf(down);
    }
}

// ---------------------------------------------------------------------------
__global__ void arc_loss(const float* __restrict__ term,
                         float* __restrict__ out)
{
    __shared__ float red[B_ROWS];
    const int b = threadIdx.x;
    red[b] = term[b];
    __syncthreads();
    #pragma unroll
    for (int st = 256; st > 0; st >>= 1) {
        if (b < st) red[b] += red[b + st];
        __syncthreads();
    }
    if (b == 0) out[0] = -red[0] / (float)B_ROWS;
}

// ---------------------------------------------------------------------------
extern "C" void kernel_launch(void* const* d_in, const int* in_sizes, int n_in,
                              void* d_out, int out_size, void* d_ws, size_t ws_size,
                              hipStream_t stream)
{
    const float* feat   = (const float*)d_in[0];   // [512,128] fp32
    const float* w      = (const float*)d_in[1];   // [128,100000] fp32
    const int*   target = (const int*)d_in[2];     // [512]

    float* pp   = (float*)d_ws;                    // [782][512], fully overwritten
    float* term = pp + (size_t)NCB * 512;          // [512]

    arc_main<<<NCB, 1024, 0, stream>>>(feat, w, pp);
    arc_row<<<B_ROWS, 64, 0, stream>>>(feat, w, target, pp, term);
    arc_loss<<<1, B_ROWS, 0, stream>>>(term, (float*)d_out);
}

// Round 5
// 131.371 us; speedup vs baseline: 2.5685x; 1.0334x over previous
//
#include <hip/hip_runtime.h>

#define F_DIM 128
#define C_DIM 100000
#define B_ROWS 512
#define ANGLE 0.5f
#define CPB 128            // classes per block
#define NCB 782            // ceil(100000/128); last block has 96 OOB pad classes
#define OOB_PAD 96.0f      // pad classes contribute exp(0)=1 each to row sums

typedef __attribute__((ext_vector_type(4))) float  f32x4;
typedef __attribute__((ext_vector_type(8))) short  bf16x8;

static __device__ __forceinline__ short f2bf(float x) {
    unsigned int u = __float_as_uint(x);
    u += 0x7FFFu + ((u >> 16) & 1u);      // RNE
    return (short)(u >> 16);
}

// ---------------------------------------------------------------------------
// arc_main: block = 8 waves = 128 classes x 256 batch rows. grid (782, 2).
//   A-operand = w^T in LDS [c][k], 16B-chunk XOR swizzle -> conflict-free
//   b128 reads AND writes. B-operand = feat fragments in registers (loaded
//   before staging; independent). 4 blocks/CU resident -> staging of one
//   block overlaps compute of three others. 8 parallel exp accumulators.
// ---------------------------------------------------------------------------
__global__ __launch_bounds__(512, 4)
void arc_main(const float* __restrict__ feat,
              const float* __restrict__ w,
              float* __restrict__ pp)        // [NCB][512]
{
    __shared__ unsigned short lBt[128 * 128];   // [c][k] swizzled, 32 KB

    const int tid = threadIdx.x;
    const int cb  = blockIdx.x;
    const int c0  = cb * CPB;
    const int r0  = blockIdx.y * 256;

    const int lane = tid & 63;
    const int wv   = tid >> 6;                // 0..7 -> 32-batch strip
    const int quad = lane >> 4;
    const int l15  = lane & 15;

    // ---- feat fragments (registers, issued before staging loads) ----
    // B-layout: fB[s][ks] = f[b][k0..k0+7], b = r0+wv*32+s*16+l15, k0=ks*32+quad*8
    bf16x8 fB[2][4];
    #pragma unroll
    for (int s = 0; s < 2; ++s) {
        const int b = r0 + wv * 32 + s * 16 + l15;
        #pragma unroll
        for (int ks = 0; ks < 4; ++ks) {
            const int k0 = ks * 32 + quad * 8;
            const f32x4 u0 = *(const f32x4*)(feat + b * F_DIM + k0);
            const f32x4 u1 = *(const f32x4*)(feat + b * F_DIM + k0 + 4);
            bf16x8 h;
            h[0] = f2bf(u0[0]); h[1] = f2bf(u0[1]); h[2] = f2bf(u0[2]); h[3] = f2bf(u0[3]);
            h[4] = f2bf(u1[0]); h[5] = f2bf(u1[1]); h[6] = f2bf(u1[2]); h[7] = f2bf(u1[3]);
            fB[s][ks] = h;
        }
    }

    // ---- stage w^T tile: thread (c, g) covers k = g*32 .. g*32+31 ----
    {
        const int c  = tid & 127;
        const int g  = tid >> 7;              // 0..3
        const int gc = c0 + c;
        #pragma unroll
        for (int j = 0; j < 4; ++j) {
            float v[8];
            #pragma unroll
            for (int i = 0; i < 8; ++i) {
                const int k = g * 32 + j * 8 + i;
                v[i] = (gc < C_DIM) ? w[(size_t)k * C_DIM + gc] : 0.f;
            }
            bf16x8 h;
            #pragma unroll
            for (int i = 0; i < 8; ++i) h[i] = f2bf(v[i]);
            const int pc = (g * 4 + j) ^ (c & 15);   // 16B-chunk XOR swizzle
            *(bf16x8*)&lBt[c * 128 + pc * 8] = h;
        }
    }
    __syncthreads();

    // ---- MFMA + exp: 8 parallel accumulators (chain length 16 each) ----
    float eA0 = 0.f, eA1 = 0.f, eA2 = 0.f, eA3 = 0.f;   // s=0 batch col
    float eB0 = 0.f, eB1 = 0.f, eB2 = 0.f, eB3 = 0.f;   // s=1 batch col
    #pragma unroll
    for (int m = 0; m < 8; ++m) {
        f32x4 a0 = {0.f, 0.f, 0.f, 0.f};
        f32x4 a1 = {0.f, 0.f, 0.f, 0.f};
        const int row = m * 16 + l15;         // class row
        #pragma unroll
        for (int ks = 0; ks < 4; ++ks) {
            const int pc = (ks * 4 + quad) ^ (row & 15);
            const bf16x8 af = *(const bf16x8*)&lBt[row * 128 + pc * 8];
            a0 = __builtin_amdgcn_mfma_f32_16x16x32_bf16(af, fB[0][ks], a0, 0, 0, 0);
            a1 = __builtin_amdgcn_mfma_f32_16x16x32_bf16(af, fB[1][ks], a1, 0, 0, 0);
        }
        eA0 += __expf(a0[0]); eA1 += __expf(a0[1]);
        eA2 += __expf(a0[2]); eA3 += __expf(a0[3]);
        eB0 += __expf(a1[0]); eB1 += __expf(a1[1]);
        eB2 += __expf(a1[2]); eB3 += __expf(a1[3]);
    }

    float esum0 = (eA0 + eA1) + (eA2 + eA3);
    float esum1 = (eB0 + eB1) + (eB2 + eB3);
    // reduce across quads (same batch col holds different class rows)
    esum0 += __shfl_xor(esum0, 16); esum0 += __shfl_xor(esum0, 32);
    esum1 += __shfl_xor(esum1, 16); esum1 += __shfl_xor(esum1, 32);
    if (lane < 16) {
        pp[(size_t)cb * 512 + r0 + wv * 32 + lane]      = esum0;
        pp[(size_t)cb * 512 + r0 + wv * 32 + 16 + lane] = esum1;
    }
}

// ---------------------------------------------------------------------------
// arc_row: exact fp32 target-column terms + partial reduce. One wave per row.
// ---------------------------------------------------------------------------
__global__ void arc_row(const float* __restrict__ feat,
                        const float* __restrict__ w,
                        const int*   __restrict__ target,
                        const float* __restrict__ pp,
                        float* __restrict__ term)
{
    const int b    = blockIdx.x;
    const int lane = threadIdx.x;             // 64
    const int t    = target[b];

    float dot = 0.f, wsq = 0.f, fsq = 0.f, rs = 0.f;
    #pragma unroll
    for (int h = 0; h < 2; ++h) {
        const int f  = lane + h * 64;
        const float fv = feat[b * F_DIM + f];
        const float wv = w[(size_t)f * C_DIM + t];
        dot += fv * wv;
        wsq += wv * wv;
        fsq += fv * fv;
    }
    for (int j = lane; j < NCB; j += 64)
        rs += pp[(size_t)j * 512 + b];

    #pragma unroll
    for (int off = 32; off > 0; off >>= 1) {
        dot += __shfl_xor(dot, off);
        wsq += __shfl_xor(wsq, off);
        fsq += __shfl_xor(fsq, off);
        rs  += __shfl_xor(rs,  off);
    }
    if (lane == 0) {
        const float mod = sqrtf(fsq) * sqrtf(wsq);
        float ct = dot / (mod * 1.01f);
        ct = fminf(1.f, fmaxf(-1.f, ct));
        const float th   = acosf(ct) + ANGLE;
        const float marg = mod * cosf(th);
        const float down = rs - OOB_PAD - expf(dot) + expf(marg);
        term[b] = marg - logf(down);
    }
}

// ---------------------------------------------------------------------------
__global__ void arc_loss(const float* __restrict__ term,
                         float* __restrict__ out)
{
    __shared__ float red[B_ROWS];
    const int b = threadIdx.x;
    red[b] = term[b];
    __syncthreads();
    #pragma unroll
    for (int st = 256; st > 0; st >>= 1) {
        if (b < st) red[b] += red[b + st];
        __syncthreads();
    }
    if (b == 0) out[0] = -red[0] / (float)B_ROWS;
}

// ---------------------------------------------------------------------------
extern "C" void kernel_launch(void* const* d_in, const int* in_sizes, int n_in,
                              void* d_out, int out_size, void* d_ws, size_t ws_size,
                              hipStream_t stream)
{
    const float* feat   = (const float*)d_in[0];   // [512,128] fp32
    const float* w      = (const float*)d_in[1];   // [128,100000] fp32
    const int*   target = (const int*)d_in[2];     // [512]

    float* pp   = (float*)d_ws;                    // [782][512], fully overwritten
    float* term = pp + (size_t)NCB * 512;          // [512]

    arc_main<<<dim3(NCB, 2), 512, 0, stream>>>(feat, w, pp);
    arc_row<<<B_ROWS, 64, 0, stream>>>(feat, w, target, pp, term);
    arc_loss<<<1, B_ROWS, 0, stream>>>(term, (float*)d_out);
}